// Round 9
// baseline (335.825 us; speedup 1.0000x reference)
//
#include <hip/hip_runtime.h>
#include <hip/hip_bf16.h>
#include <math.h>

// B=2, T=2048, C=1024, H=16, HD=64. M = B*T = 4096 rows.
// Split-bf16 (Ootomo) MFMA: fp32 product = ah*bh + ah*bl + al*bh (3 MFMAs).
// Attention PV uses P-hi only; V hi+lo (2 MFMAs).
// Round 9 (= round 8 resubmitted after GPU timeout; desk-audited):
// attn re-partitioned 256->512 threads (8 waves x 16 q-rows). Same QBLK=128,
// same LDS 64KB (K/V dbuf; P-hi in dead K[cur], 8 x 2KB slices), same
// swizzles. Halves per-wave serial softmax, doubles waves/SIMD for latency
// hiding. GEMMs unchanged.
// Workspace (base 64 MB; [64,80)MB x-presplit engaged when ws allows):
//   [ 0, 8)MB Qh   [ 8,16)MB Ql    (pre-scaled 0.125*log2e; aliased as AO after attn)
//   [16,24)MB Kh   [24,32)MB Kl    [b,t, h*64+d]
//   [32,40)MB Vth  [40,48)MB Vtl   [b,h,d,t]
//   [48,64)MB wqh,wql,wkh,wkl,wvh,wvl,woh,wol (2MB each, W^T [N][K])
//   [64,72)MB xh   [72,80)MB xl    (only if ws_size >= 80MB)

typedef __attribute__((ext_vector_type(8))) short short8;  // 8 bf16 = 4 VGPR
typedef __attribute__((ext_vector_type(4))) float f32x4;   // mfma acc
union U8 { short8 s8; unsigned u[4]; };

#define MFMA16(A, B, C) __builtin_amdgcn_mfma_f32_16x16x32_bf16(A, B, C, 0, 0, 0)

// XOR swizzles — involutions, applied on BOTH write/source and read side (rule #21)
#define SW4(s, r) (((s) ^ (r) ^ ((r) >> 2)) & 3)  // 4 x 16B units per row
#define SW8(s, r) (((s) ^ (r)) & 7)               // 8 x 16B slots per row

static __device__ __forceinline__ unsigned pk2(float f0, float f1) {
  union { __hip_bfloat162 b; unsigned u; } c;
  c.b = __float22bfloat162_rn(make_float2(f0, f1));  // f0 -> low16, f1 -> high16
  return c.u;
}
static __device__ __forceinline__ void splitpk(float f0, float f1,
                                               unsigned& uh, unsigned& ul) {
  unsigned h = pk2(f0, f1);
  float r0 = f0 - __uint_as_float(h << 16);
  float r1 = f1 - __uint_as_float(h & 0xffff0000u);
  uh = h;
  ul = pk2(r0, r1);
}
static __device__ __forceinline__ void gl_lds16(const void* g, void* l) {
  __builtin_amdgcn_global_load_lds(
      (const __attribute__((address_space(1))) void*)g,
      (__attribute__((address_space(3))) void*)l, 16, 0, 0);
}

// ---------------- prep: W [K][N] fp32 -> W^T hi/lo bf16 [N][K] ----------------
__global__ __launch_bounds__(256) void wprep(
    const float* __restrict__ Wq, const float* __restrict__ Wk,
    const float* __restrict__ Wv, const float* __restrict__ Wo,
    ushort* qh, ushort* ql, ushort* kh, ushort* kl,
    ushort* vh, ushort* vl, ushort* oh, ushort* ol)
{
  __shared__ float T[64][65];
  const int z = blockIdx.z;
  const float* W = (z == 0) ? Wq : (z == 1) ? Wk : (z == 2) ? Wv : Wo;
  ushort* H = (z == 0) ? qh : (z == 1) ? kh : (z == 2) ? vh : oh;
  ushort* L = (z == 0) ? ql : (z == 1) ? kl : (z == 2) ? vl : ol;
  const int k0 = blockIdx.x * 64, n0 = blockIdx.y * 64;
  const int tid = threadIdx.x;
  const int rr = tid >> 4, c4 = (tid & 15) * 4;
#pragma unroll
  for (int p = 0; p < 4; ++p) {
    float4 v = *(const float4*)&W[(size_t)(k0 + p * 16 + rr) * 1024 + n0 + c4];
    T[p * 16 + rr][c4 + 0] = v.x; T[p * 16 + rr][c4 + 1] = v.y;
    T[p * 16 + rr][c4 + 2] = v.z; T[p * 16 + rr][c4 + 3] = v.w;
  }
  __syncthreads();
#pragma unroll
  for (int p = 0; p < 4; ++p) {
    int nr = p * 16 + rr;
    unsigned uh01, ul01, uh23, ul23;
    splitpk(T[c4 + 0][nr], T[c4 + 1][nr], uh01, ul01);
    splitpk(T[c4 + 2][nr], T[c4 + 3][nr], uh23, ul23);
    size_t a = (size_t)(n0 + nr) * 1024 + k0 + c4;
    *(uint2*)&H[a] = make_uint2(uh01, uh23);
    *(uint2*)&L[a] = make_uint2(ul01, ul23);
  }
}

// ---------------- prep: x fp32 -> xh/xl bf16 (only if ws allows) --------------
__global__ __launch_bounds__(256) void xsplit(const float* __restrict__ x,
                                              ushort* __restrict__ xh,
                                              ushort* __restrict__ xl)
{
  size_t i = (size_t)blockIdx.x * 256 + threadIdx.x;  // over 1M float4
  float4 v = *(const float4*)&x[i * 4];
  unsigned uh01, ul01, uh23, ul23;
  splitpk(v.x, v.y, uh01, ul01);
  splitpk(v.z, v.w, uh23, ul23);
  *(uint2*)&xh[i * 4] = make_uint2(uh01, uh23);
  *(uint2*)&xl[i * 4] = make_uint2(ul01, ul23);
}

// ---------------- 128x128 MFMA GEMM core (K=1024), 4 waves 2x2, BK=32 ----------
// 2-phase double-buffered: stage(next) issued after barrier, drained at the
// NEXT barrier (loads in flight across the whole compute phase).
template <bool AFP32>
__device__ __forceinline__ void gemm_core(
    const void* A0, const void* A1,
    const ushort* __restrict__ Bh, const ushort* __restrict__ Bl,
    int m0, int n0, f32x4 (&acc)[4][4])
{
  __shared__ __align__(16) char SM[2][32768];
  const int tid = threadIdx.x, lane = tid & 63, w = tid >> 6;
  const int wm = w >> 1, wn = w & 1;
  const int r16 = lane & 15, kg = lane >> 4;

  auto stage = [&](char* S, int k0) {
    if constexpr (AFP32) {
      if (w < 2) {  // A fp32 [128][32] -> S[0,16384), 128B rows
        const float* A = (const float*)A0;
        const int lr8 = lane >> 3, ls = lane & 7;
        const int u = ls >> 1, hf = (ls & 1) * 4;
#pragma unroll
        for (int c = 0; c < 8; ++c) {
          const int row = w * 64 + c * 8 + lr8;
          const float* g = A + (size_t)(m0 + row) * 1024 + k0 + SW4(u, row) * 8 + hf;
          gl_lds16(g, S + w * 8192 + c * 1024);
        }
      } else {      // Bh/Bl [128][32] ushort -> S[16384,32768), 64B rows
        const ushort* src = (w == 2) ? Bh : Bl;
        const int lr = lane >> 2, ls = lane & 3;
#pragma unroll
        for (int c = 0; c < 8; ++c) {
          const int row = c * 16 + lr;
          const ushort* g = src + (size_t)(n0 + row) * 1024 + k0 + SW4(ls, row) * 8;
          gl_lds16(g, S + 16384 + (w - 2) * 8192 + c * 1024);
        }
      }
    } else {        // 4 buffers Ah/Al/Bh/Bl, one per wave
      const ushort* src = (w == 0) ? (const ushort*)A0
                        : (w == 1) ? (const ushort*)A1
                        : (w == 2) ? Bh : Bl;
      const int rbase = (w < 2) ? m0 : n0;
      const int lr = lane >> 2, ls = lane & 3;
#pragma unroll
      for (int c = 0; c < 8; ++c) {
        const int row = c * 16 + lr;
        const ushort* g = src + (size_t)(rbase + row) * 1024 + k0 + SW4(ls, row) * 8;
        gl_lds16(g, S + w * 8192 + c * 1024);
      }
    }
  };

  stage(SM[0], 0);  // prologue

  for (int k0 = 0; k0 < 1024; k0 += 32) {
    char* CUR = SM[(k0 >> 5) & 1];
    __syncthreads();  // drains prev stage (vmcnt0) + all waves done reading other buf
    if (k0 + 32 < 1024) stage(SM[((k0 >> 5) & 1) ^ 1], k0 + 32);

    short8 ah[4], al[4], bh[4], bl[4];
    if constexpr (AFP32) {
      const float* SA = (const float*)CUR;
#pragma unroll
      for (int f = 0; f < 4; ++f) {
        const int ra = wm * 64 + f * 16 + r16;
        const int ad = ra * 32 + SW4(kg, ra) * 8;
        f32x4 x0 = *(const f32x4*)&SA[ad];
        f32x4 x1 = *(const f32x4*)&SA[ad + 4];
        U8 H, L;
        splitpk(x0[0], x0[1], H.u[0], L.u[0]);
        splitpk(x0[2], x0[3], H.u[1], L.u[1]);
        splitpk(x1[0], x1[1], H.u[2], L.u[2]);
        splitpk(x1[2], x1[3], H.u[3], L.u[3]);
        ah[f] = H.s8; al[f] = L.s8;
      }
      const ushort* SBh = (const ushort*)(CUR + 16384);
      const ushort* SBl = (const ushort*)(CUR + 24576);
#pragma unroll
      for (int f = 0; f < 4; ++f) {
        const int rb = wn * 64 + f * 16 + r16;
        const int ab = rb * 32 + SW4(kg, rb) * 8;
        bh[f] = *(const short8*)&SBh[ab];
        bl[f] = *(const short8*)&SBl[ab];
      }
    } else {
      const ushort* SAh = (const ushort*)CUR;
      const ushort* SAl = (const ushort*)(CUR + 8192);
      const ushort* SBh = (const ushort*)(CUR + 16384);
      const ushort* SBl = (const ushort*)(CUR + 24576);
#pragma unroll
      for (int f = 0; f < 4; ++f) {
        const int ra = wm * 64 + f * 16 + r16;
        const int aa = ra * 32 + SW4(kg, ra) * 8;
        ah[f] = *(const short8*)&SAh[aa];
        al[f] = *(const short8*)&SAl[aa];
        const int rb = wn * 64 + f * 16 + r16;
        const int ab = rb * 32 + SW4(kg, rb) * 8;
        bh[f] = *(const short8*)&SBh[ab];
        bl[f] = *(const short8*)&SBl[ab];
      }
    }
    __builtin_amdgcn_s_setprio(1);
#pragma unroll
    for (int i = 0; i < 4; ++i)
#pragma unroll
      for (int j = 0; j < 4; ++j) {
        acc[i][j] = MFMA16(ah[i], bh[j], acc[i][j]);
        acc[i][j] = MFMA16(ah[i], bl[j], acc[i][j]);
        acc[i][j] = MFMA16(al[i], bh[j], acc[i][j]);
      }
    __builtin_amdgcn_s_setprio(0);
  }
}

// ---------------- QKV projection -------------------------------------------
template <bool PRESPLIT>
__global__ __launch_bounds__(256) void qkv_gemm(
    const float* __restrict__ x,
    const ushort* __restrict__ xh, const ushort* __restrict__ xl,
    const ushort* __restrict__ wqh, const ushort* __restrict__ wql,
    const ushort* __restrict__ wkh, const ushort* __restrict__ wkl,
    const ushort* __restrict__ wvh, const ushort* __restrict__ wvl,
    const float* __restrict__ bq, const float* __restrict__ bk,
    const float* __restrict__ bv,
    ushort* __restrict__ Qh, ushort* __restrict__ Ql,
    ushort* __restrict__ Kh, ushort* __restrict__ Kl,
    ushort* __restrict__ Vth, ushort* __restrict__ Vtl)
{
  const int ts = blockIdx.x >> 3;            // 0=Q 1=K 2=V
  const int n0 = (blockIdx.x & 7) * 128;
  const int m0 = blockIdx.y * 128;
  const ushort* Bh = (ts == 0) ? wqh : (ts == 1) ? wkh : wvh;
  const ushort* Bl = (ts == 0) ? wql : (ts == 1) ? wkl : wvl;
  const float* bias = (ts == 0) ? bq : (ts == 1) ? bk : bv;

  f32x4 zv = {0.f, 0.f, 0.f, 0.f};
  f32x4 acc[4][4];
#pragma unroll
  for (int i = 0; i < 4; ++i)
#pragma unroll
    for (int j = 0; j < 4; ++j) acc[i][j] = zv;

  if constexpr (PRESPLIT)
    gemm_core<false>(xh, xl, Bh, Bl, m0, n0, acc);
  else
    gemm_core<true>(x, nullptr, Bh, Bl, m0, n0, acc);

  const int lane = threadIdx.x & 63, w = threadIdx.x >> 6;
  const int wm = w >> 1, wn = w & 1, r16 = lane & 15, g4 = (lane >> 4) * 4;
  // Q pre-scale folds 1/sqrt(64) AND log2(e): softmax runs in exp2 domain.
  const float scale = (ts == 0) ? 0.18033688011112042f : 1.0f;
  ushort* H = (ts == 0) ? Qh : Kh;
  ushort* L = (ts == 0) ? Ql : Kl;
#pragma unroll
  for (int j = 0; j < 4; ++j) {
    const int nc = n0 + wn * 64 + j * 16 + r16;
    const float bb = bias[nc];
#pragma unroll
    for (int i = 0; i < 4; ++i) {
      const int mr = m0 + wm * 64 + i * 16 + g4;
      float v0 = (acc[i][j][0] + bb) * scale;
      float v1 = (acc[i][j][1] + bb) * scale;
      float v2 = (acc[i][j][2] + bb) * scale;
      float v3 = (acc[i][j][3] + bb) * scale;
      unsigned uh01, ul01, uh23, ul23;
      splitpk(v0, v1, uh01, ul01);
      splitpk(v2, v3, uh23, ul23);
      if (ts < 2) {      // Q/K: [b,t, h*64+d]
        size_t a0 = (size_t)mr * 1024 + nc;
        H[a0]        = (ushort)(uh01 & 0xffffu);
        H[a0 + 1024] = (ushort)(uh01 >> 16);
        H[a0 + 2048] = (ushort)(uh23 & 0xffffu);
        H[a0 + 3072] = (ushort)(uh23 >> 16);
        L[a0]        = (ushort)(ul01 & 0xffffu);
        L[a0 + 1024] = (ushort)(ul01 >> 16);
        L[a0 + 2048] = (ushort)(ul23 & 0xffffu);
        L[a0 + 3072] = (ushort)(ul23 >> 16);
      } else {           // V transposed scatter [b,h,d,t]
        const int b = mr >> 11, t0 = mr & 2047;
        const int hh = nc >> 6, d = nc & 63;
        size_t a0 = ((size_t)((b * 16 + hh) * 64 + d)) * 2048 + t0;
        *(unsigned*)&Vth[a0]     = uh01;
        *(unsigned*)&Vth[a0 + 2] = uh23;
        *(unsigned*)&Vtl[a0]     = ul01;
        *(unsigned*)&Vtl[a0 + 2] = ul23;
      }
    }
  }
}

// ---------------- flash attention (causal), split-bf16 MFMA --------------------
// 512 thr = 8 waves x 16 q-rows (QBLK=128); KV tile 64; double-buffered K/V.
// LDS = 64KB. P-hi reuses the dead K[cur] tile (8 x 2KB wave slices) after a
// mid-tile lgkm-only raw barrier (keeps prefetch vmcnt in flight).
__global__ __launch_bounds__(512, 4) void attn(
    const ushort* __restrict__ Qh, const ushort* __restrict__ Ql,
    const ushort* __restrict__ Kgh, const ushort* __restrict__ Kgl,
    const ushort* __restrict__ Vth, const ushort* __restrict__ Vtl,
    ushort* __restrict__ AOh, ushort* __restrict__ AOl)
{
  // [buf][component: 0=Kh 1=Kl 2=Vh 3=Vl][64*64]
  __shared__ __align__(16) ushort KV[2][4][64 * 64];

  const int id = blockIdx.x;
  const int bh = id & 31;
  const int qr = id >> 5;                    // 0..15
  const int qt = (qr < 8) ? qr : 23 - qr;    // blocks (id, id+256) complementary
  const int b = bh >> 4, h = bh & 15;
  const int q0 = qt * 128;

  const int tid = threadIdx.x, lane = tid & 63, w = tid >> 6;  // w in 0..7
  const int r16 = lane & 15, lg = lane >> 4;
  const int lr8 = lane >> 3, ls8 = lane & 7;

  // 8-wave staging: wave w stages half (w&1) of component (w>>1).
  auto stageKV = [&](ushort (&BUF)[4][64 * 64], int k0) {
    const int comp = w >> 1;     // 0=Kh 1=Kl 2=Vh 3=Vl
    const int half = w & 1;      // rows 0-31 / 32-63
    char* dst = (char*)BUF[comp] + half * 4096;
    if (comp < 2) {              // K: LDS [t][64d], source d-slot swizzled
      const ushort* src = (comp == 0) ? Kgh : Kgl;
#pragma unroll
      for (int cc = 0; cc < 4; ++cc) {
        const int t = half * 32 + cc * 8 + lr8;
        const ushort* g = src + (size_t)(b * 2048 + k0 + t) * 1024 + h * 64 + SW8(ls8, t) * 8;
        gl_lds16(g, dst + cc * 1024);
      }
    } else {                     // V: LDS [d][64t], source t-slot swizzled
      const ushort* src = (comp == 2) ? Vth : Vtl;
#pragma unroll
      for (int cc = 0; cc < 4; ++cc) {
        const int d = half * 32 + cc * 8 + lr8;
        const ushort* g = src + (size_t)(bh * 64 + d) * 2048 + k0 + SW8(ls8, d) * 8;
        gl_lds16(g, dst + cc * 1024);
      }
    }
  };

  // Q fragments (pre-scaled, pre-split). A-frag: row=lane&15, k=(lane>>4)*8+j (+32s)
  short8 qfh[2], qfl[2];
#pragma unroll
  for (int s = 0; s < 2; ++s) {
    const int q = q0 + w * 16 + r16;
    size_t a = (size_t)(b * 2048 + q) * 1024 + h * 64 + 32 * s + lg * 8;
    qfh[s] = *(const short8*)&Qh[a];
    qfl[s] = *(const short8*)&Ql[a];
  }

  f32x4 zv = {0.f, 0.f, 0.f, 0.f};
  f32x4 o[4];
  float m_run[4], l_run[4];
#pragma unroll
  for (int nf = 0; nf < 4; ++nf) o[nf] = zv;
#pragma unroll
  for (int r = 0; r < 4; ++r) { m_run[r] = -INFINITY; l_run[r] = 0.f; }

  stageKV(KV[0], 0);  // prologue

  for (int k0 = 0; k0 < q0 + 128; k0 += 64) {
    const int pb = (k0 >> 6) & 1;
    __syncthreads();  // drains prev stage; all waves done reading other buf
    if (k0 + 64 < q0 + 128) stageKV(KV[pb ^ 1], k0 + 64);
    const ushort* KhL = KV[pb][0];
    const ushort* KlL = KV[pb][1];
    const ushort* VhL = KV[pb][2];
    const ushort* VlL = KV[pb][3];
    // wave-private 2KB P slice inside the (soon dead) K[cur] tile
    ushort* php = &KV[pb][w >> 2][(w & 3) * 1024];

    // S = Q K^T (3-term split)
    f32x4 sf[4];
#pragma unroll
    for (int nf = 0; nf < 4; ++nf) sf[nf] = zv;
#pragma unroll
    for (int s = 0; s < 2; ++s) {
      short8 kh_[4], kl_[4];
#pragma unroll
      for (int nf = 0; nf < 4; ++nf) {
        const int kv = nf * 16 + r16;
        const int ad = kv * 64 + SW8(4 * s + lg, kv) * 8;
        kh_[nf] = *(const short8*)&KhL[ad];
        kl_[nf] = *(const short8*)&KlL[ad];
      }
      __builtin_amdgcn_s_setprio(1);
#pragma unroll
      for (int nf = 0; nf < 4; ++nf) {
        sf[nf] = MFMA16(qfh[s], kh_[nf], sf[nf]);
        sf[nf] = MFMA16(qfh[s], kl_[nf], sf[nf]);
        sf[nf] = MFMA16(qfl[s], kh_[nf], sf[nf]);
      }
      __builtin_amdgcn_s_setprio(0);
    }

    // Mid-tile barrier: all waves' K ds_reads complete (lgkm only — the
    // in-flight global_load_lds prefetch is vmcnt and stays in flight).
    asm volatile("s_waitcnt lgkmcnt(0)\n\ts_barrier" ::: "memory");

    // causal mask + online softmax (exp2 domain); C/D: row=(lane>>4)*4+r, col=lane&15
#pragma unroll
    for (int r = 0; r < 4; ++r) {
      const int qg = q0 + w * 16 + lg * 4 + r;
#pragma unroll
      for (int nf = 0; nf < 4; ++nf) {
        const int kvg = k0 + nf * 16 + r16;
        if (kvg > qg) sf[nf][r] = -INFINITY;
      }
      float mx = fmaxf(fmaxf(sf[0][r], sf[1][r]), fmaxf(sf[2][r], sf[3][r]));
      mx = fmaxf(mx, __shfl_xor(mx, 1));
      mx = fmaxf(mx, __shfl_xor(mx, 2));
      mx = fmaxf(mx, __shfl_xor(mx, 4));
      mx = fmaxf(mx, __shfl_xor(mx, 8));
      const float mn = fmaxf(m_run[r], mx);
      const float al_ = __builtin_amdgcn_exp2f(m_run[r] - mn);
      float ps = 0.f;
#pragma unroll
      for (int nf = 0; nf < 4; ++nf) {
        const float p = __builtin_amdgcn_exp2f(sf[nf][r] - mn);
        sf[nf][r] = p;
        ps += p;
      }
      ps += __shfl_xor(ps, 1); ps += __shfl_xor(ps, 2);
      ps += __shfl_xor(ps, 4); ps += __shfl_xor(ps, 8);
      l_run[r] = l_run[r] * al_ + ps;
      m_run[r] = mn;
#pragma unroll
      for (int nf = 0; nf < 4; ++nf) o[nf][r] *= al_;
      // stage P hi (wave-private slice, swizzled; same-wave RAW, no barrier)
      const unsigned uh01 = pk2(sf[0][r], sf[1][r]);
      const unsigned uh23 = pk2(sf[2][r], sf[3][r]);
      const int row = lg * 4 + r;
      const int p7 = r16 & 7, hi8 = r16 >> 3;
      php[row * 64 + SW8(0 + hi8, row) * 8 + p7] = (ushort)(uh01 & 0xffffu);
      php[row * 64 + SW8(2 + hi8, row) * 8 + p7] = (ushort)(uh01 >> 16);
      php[row * 64 + SW8(4 + hi8, row) * 8 + p7] = (ushort)(uh23 & 0xffffu);
      php[row * 64 + SW8(6 + hi8, row) * 8 + p7] = (ushort)(uh23 >> 16);
    }

    // O += P V (P hi only; V hi+lo)
#pragma unroll
    for (int s2 = 0; s2 < 2; ++s2) {
      const int pad = r16 * 64 + SW8(4 * s2 + lg, r16) * 8;
      const short8 ph_ = *(const short8*)&php[pad];
      short8 vh_[4], vl_[4];
#pragma unroll
      for (int nf = 0; nf < 4; ++nf) {
        const int d = nf * 16 + r16;
        const int ad = d * 64 + SW8(4 * s2 + lg, d) * 8;
        vh_[nf] = *(const short8*)&VhL[ad];
        vl_[nf] = *(const short8*)&VlL[ad];
      }
      __builtin_amdgcn_s_setprio(1);
#pragma unroll
      for (int nf = 0; nf < 4; ++nf) {
        o[nf] = MFMA16(ph_, vh_[nf], o[nf]);
        o[nf] = MFMA16(ph_, vl_[nf], o[nf]);
      }
      __builtin_amdgcn_s_setprio(0);
    }
  }

  // epilogue: normalize, split, write AO hi/lo (aliases Qh/Ql — disjoint ownership)
#pragma unroll
  for (int r = 0; r < 4; ++r) {
    const float inv = 1.f / l_run[r];
    const int q = q0 + w * 16 + lg * 4 + r;
    const size_t base = (size_t)(b * 2048 + q) * 1024 + h * 64;
    unsigned uh01, ul01, uh23, ul23;
    splitpk(o[0][r] * inv, o[1][r] * inv, uh01, ul01);
    splitpk(o[2][r] * inv, o[3][r] * inv, uh23, ul23);
    AOh[base + r16]      = (ushort)(uh01 & 0xffffu);
    AOh[base + 16 + r16] = (ushort)(uh01 >> 16);
    AOh[base + 32 + r16] = (ushort)(uh23 & 0xffffu);
    AOh[base + 48 + r16] = (ushort)(uh23 >> 16);
    AOl[base + r16]      = (ushort)(ul01 & 0xffffu);
    AOl[base + 16 + r16] = (ushort)(ul01 >> 16);
    AOl[base + 32 + r16] = (ushort)(ul23 & 0xffffu);
    AOl[base + 48 + r16] = (ushort)(ul23 >> 16);
  }
}

// ---------------- output projection: AO @ Wo + bo -> out (fp32) ----------------
__global__ __launch_bounds__(256) void proj_gemm(
    const ushort* __restrict__ aoh, const ushort* __restrict__ aol,
    const ushort* __restrict__ woh, const ushort* __restrict__ wol,
    const float* __restrict__ bo, float* __restrict__ out)
{
  const int n0 = blockIdx.x * 128, m0 = blockIdx.y * 128;
  f32x4 zv = {0.f, 0.f, 0.f, 0.f};
  f32x4 acc[4][4];
#pragma unroll
  for (int i = 0; i < 4; ++i)
#pragma unroll
    for (int j = 0; j < 4; ++j) acc[i][j] = zv;

  gemm_core<false>(aoh, aol, woh, wol, m0, n0, acc);

  const int lane = threadIdx.x & 63, w = threadIdx.x >> 6;
  const int wm = w >> 1, wn = w & 1, r16 = lane & 15, g4 = (lane >> 4) * 4;
#pragma unroll
  for (int j = 0; j < 4; ++j) {
    const int nc = n0 + wn * 64 + j * 16 + r16;
    const float bb = bo[nc];
#pragma unroll
    for (int i = 0; i < 4; ++i) {
      const int mr = m0 + wm * 64 + i * 16 + g4;
#pragma unroll
      for (int r = 0; r < 4; ++r)
        out[(size_t)(mr + r) * 1024 + nc] = acc[i][j][r] + bb;
    }
  }
}

extern "C" void kernel_launch(void* const* d_in, const int* in_sizes, int n_in,
                              void* d_out, int out_size, void* d_ws, size_t ws_size,
                              hipStream_t stream) {
  const float* x  = (const float*)d_in[0];
  const float* Wq = (const float*)d_in[1];
  const float* bq = (const float*)d_in[2];
  const float* Wk = (const float*)d_in[3];
  const float* bk = (const float*)d_in[4];
  const float* Wv = (const float*)d_in[5];
  const float* bv = (const float*)d_in[6];
  const float* Wo = (const float*)d_in[7];
  const float* bo = (const float*)d_in[8];
  float* out = (float*)d_out;
  (void)in_sizes; (void)n_in; (void)out_size;

  const size_t MB = 1u << 20;
  char* ws = (char*)d_ws;
  ushort* Qh  = (ushort*)(ws + 0 * MB);
  ushort* Ql  = (ushort*)(ws + 8 * MB);
  ushort* Kh  = (ushort*)(ws + 16 * MB);
  ushort* Kl  = (ushort*)(ws + 24 * MB);
  ushort* Vth = (ushort*)(ws + 32 * MB);
  ushort* Vtl = (ushort*)(ws + 40 * MB);
  ushort* wqh = (ushort*)(ws + 48 * MB);
  ushort* wql = (ushort*)(ws + 50 * MB);
  ushort* wkh = (ushort*)(ws + 52 * MB);
  ushort* wkl = (ushort*)(ws + 54 * MB);
  ushort* wvh = (ushort*)(ws + 56 * MB);
  ushort* wvl = (ushort*)(ws + 58 * MB);
  ushort* woh = (ushort*)(ws + 60 * MB);
  ushort* wol = (ushort*)(ws + 62 * MB);
  ushort* AOh = Qh;   // alias: attn writes exactly the Q region it owns
  ushort* AOl = Ql;

  wprep<<<dim3(16, 16, 4), 256, 0, stream>>>(Wq, Wk, Wv, Wo,
                                             wqh, wql, wkh, wkl, wvh, wvl, woh, wol);
  if (ws_size >= 80 * MB) {
    ushort* xh = (ushort*)(ws + 64 * MB);
    ushort* xl = (ushort*)(ws + 72 * MB);
    xsplit<<<dim3(4096), 256, 0, stream>>>(x, xh, xl);
    qkv_gemm<true><<<dim3(24, 32), 256, 0, stream>>>(
        x, xh, xl, wqh, wql, wkh, wkl, wvh, wvl, bq, bk, bv,
        Qh, Ql, Kh, Kl, Vth, Vtl);
  } else {
    qkv_gemm<false><<<dim3(24, 32), 256, 0, stream>>>(
        x, nullptr, nullptr, wqh, wql, wkh, wkl, wvh, wvl, bq, bk, bv,
        Qh, Ql, Kh, Kl, Vth, Vtl);
  }
  attn<<<dim3(512), 512, 0, stream>>>(Qh, Ql, Kh, Kl, Vth, Vtl, AOh, AOl);
  proj_gemm<<<dim3(8, 32), 256, 0, stream>>>(AOh, AOl, woh, wol, bo, out);
}

// Round 10
// 293.734 us; speedup vs baseline: 1.1433x; 1.1433x over previous
//
#include <hip/hip_runtime.h>
#include <hip/hip_bf16.h>
#include <math.h>

// B=2, T=2048, C=1024, H=16, HD=64. M = B*T = 4096 rows.
// Split-bf16 (Ootomo) MFMA: fp32 product = ah*bh + ah*bl + al*bh (3 MFMAs).
// Attention PV uses P-hi only; V hi+lo (2 MFMAs).
// Round 10: identical to round 9 EXCEPT attn __launch_bounds__(512,4) ->
// __launch_bounds__(512). Round 9's counters showed the ",4" forced VGPR=64
// and spilled (~31MB/dispatch extra HBM traffic: WRITE 16->38MB, FETCH
// 25->35MB). Plain bounds let the allocator use ~100-128 VGPR (4 waves/SIMD
// retained, no scratch).
// Workspace (base 64 MB; [64,80)MB x-presplit engaged when ws allows):
//   [ 0, 8)MB Qh   [ 8,16)MB Ql    (pre-scaled 0.125*log2e; aliased as AO after attn)
//   [16,24)MB Kh   [24,32)MB Kl    [b,t, h*64+d]
//   [32,40)MB Vth  [40,48)MB Vtl   [b,h,d,t]
//   [48,64)MB wqh,wql,wkh,wkl,wvh,wvl,woh,wol (2MB each, W^T [N][K])
//   [64,72)MB xh   [72,80)MB xl    (only if ws_size >= 80MB)

typedef __attribute__((ext_vector_type(8))) short short8;  // 8 bf16 = 4 VGPR
typedef __attribute__((ext_vector_type(4))) float f32x4;   // mfma acc
union U8 { short8 s8; unsigned u[4]; };

#define MFMA16(A, B, C) __builtin_amdgcn_mfma_f32_16x16x32_bf16(A, B, C, 0, 0, 0)

// XOR swizzles — involutions, applied on BOTH write/source and read side (rule #21)
#define SW4(s, r) (((s) ^ (r) ^ ((r) >> 2)) & 3)  // 4 x 16B units per row
#define SW8(s, r) (((s) ^ (r)) & 7)               // 8 x 16B slots per row

static __device__ __forceinline__ unsigned pk2(float f0, float f1) {
  union { __hip_bfloat162 b; unsigned u; } c;
  c.b = __float22bfloat162_rn(make_float2(f0, f1));  // f0 -> low16, f1 -> high16
  return c.u;
}
static __device__ __forceinline__ void splitpk(float f0, float f1,
                                               unsigned& uh, unsigned& ul) {
  unsigned h = pk2(f0, f1);
  float r0 = f0 - __uint_as_float(h << 16);
  float r1 = f1 - __uint_as_float(h & 0xffff0000u);
  uh = h;
  ul = pk2(r0, r1);
}
static __device__ __forceinline__ void gl_lds16(const void* g, void* l) {
  __builtin_amdgcn_global_load_lds(
      (const __attribute__((address_space(1))) void*)g,
      (__attribute__((address_space(3))) void*)l, 16, 0, 0);
}

// ---------------- prep: W [K][N] fp32 -> W^T hi/lo bf16 [N][K] ----------------
__global__ __launch_bounds__(256) void wprep(
    const float* __restrict__ Wq, const float* __restrict__ Wk,
    const float* __restrict__ Wv, const float* __restrict__ Wo,
    ushort* qh, ushort* ql, ushort* kh, ushort* kl,
    ushort* vh, ushort* vl, ushort* oh, ushort* ol)
{
  __shared__ float T[64][65];
  const int z = blockIdx.z;
  const float* W = (z == 0) ? Wq : (z == 1) ? Wk : (z == 2) ? Wv : Wo;
  ushort* H = (z == 0) ? qh : (z == 1) ? kh : (z == 2) ? vh : oh;
  ushort* L = (z == 0) ? ql : (z == 1) ? kl : (z == 2) ? vl : ol;
  const int k0 = blockIdx.x * 64, n0 = blockIdx.y * 64;
  const int tid = threadIdx.x;
  const int rr = tid >> 4, c4 = (tid & 15) * 4;
#pragma unroll
  for (int p = 0; p < 4; ++p) {
    float4 v = *(const float4*)&W[(size_t)(k0 + p * 16 + rr) * 1024 + n0 + c4];
    T[p * 16 + rr][c4 + 0] = v.x; T[p * 16 + rr][c4 + 1] = v.y;
    T[p * 16 + rr][c4 + 2] = v.z; T[p * 16 + rr][c4 + 3] = v.w;
  }
  __syncthreads();
#pragma unroll
  for (int p = 0; p < 4; ++p) {
    int nr = p * 16 + rr;
    unsigned uh01, ul01, uh23, ul23;
    splitpk(T[c4 + 0][nr], T[c4 + 1][nr], uh01, ul01);
    splitpk(T[c4 + 2][nr], T[c4 + 3][nr], uh23, ul23);
    size_t a = (size_t)(n0 + nr) * 1024 + k0 + c4;
    *(uint2*)&H[a] = make_uint2(uh01, uh23);
    *(uint2*)&L[a] = make_uint2(ul01, ul23);
  }
}

// ---------------- prep: x fp32 -> xh/xl bf16 (only if ws allows) --------------
__global__ __launch_bounds__(256) void xsplit(const float* __restrict__ x,
                                              ushort* __restrict__ xh,
                                              ushort* __restrict__ xl)
{
  size_t i = (size_t)blockIdx.x * 256 + threadIdx.x;  // over 1M float4
  float4 v = *(const float4*)&x[i * 4];
  unsigned uh01, ul01, uh23, ul23;
  splitpk(v.x, v.y, uh01, ul01);
  splitpk(v.z, v.w, uh23, ul23);
  *(uint2*)&xh[i * 4] = make_uint2(uh01, uh23);
  *(uint2*)&xl[i * 4] = make_uint2(ul01, ul23);
}

// ---------------- 128x128 MFMA GEMM core (K=1024), 4 waves 2x2, BK=32 ----------
// 2-phase double-buffered: stage(next) issued after barrier, drained at the
// NEXT barrier (loads in flight across the whole compute phase).
template <bool AFP32>
__device__ __forceinline__ void gemm_core(
    const void* A0, const void* A1,
    const ushort* __restrict__ Bh, const ushort* __restrict__ Bl,
    int m0, int n0, f32x4 (&acc)[4][4])
{
  __shared__ __align__(16) char SM[2][32768];
  const int tid = threadIdx.x, lane = tid & 63, w = tid >> 6;
  const int wm = w >> 1, wn = w & 1;
  const int r16 = lane & 15, kg = lane >> 4;

  auto stage = [&](char* S, int k0) {
    if constexpr (AFP32) {
      if (w < 2) {  // A fp32 [128][32] -> S[0,16384), 128B rows
        const float* A = (const float*)A0;
        const int lr8 = lane >> 3, ls = lane & 7;
        const int u = ls >> 1, hf = (ls & 1) * 4;
#pragma unroll
        for (int c = 0; c < 8; ++c) {
          const int row = w * 64 + c * 8 + lr8;
          const float* g = A + (size_t)(m0 + row) * 1024 + k0 + SW4(u, row) * 8 + hf;
          gl_lds16(g, S + w * 8192 + c * 1024);
        }
      } else {      // Bh/Bl [128][32] ushort -> S[16384,32768), 64B rows
        const ushort* src = (w == 2) ? Bh : Bl;
        const int lr = lane >> 2, ls = lane & 3;
#pragma unroll
        for (int c = 0; c < 8; ++c) {
          const int row = c * 16 + lr;
          const ushort* g = src + (size_t)(n0 + row) * 1024 + k0 + SW4(ls, row) * 8;
          gl_lds16(g, S + 16384 + (w - 2) * 8192 + c * 1024);
        }
      }
    } else {        // 4 buffers Ah/Al/Bh/Bl, one per wave
      const ushort* src = (w == 0) ? (const ushort*)A0
                        : (w == 1) ? (const ushort*)A1
                        : (w == 2) ? Bh : Bl;
      const int rbase = (w < 2) ? m0 : n0;
      const int lr = lane >> 2, ls = lane & 3;
#pragma unroll
      for (int c = 0; c < 8; ++c) {
        const int row = c * 16 + lr;
        const ushort* g = src + (size_t)(rbase + row) * 1024 + k0 + SW4(ls, row) * 8;
        gl_lds16(g, S + w * 8192 + c * 1024);
      }
    }
  };

  stage(SM[0], 0);  // prologue

  for (int k0 = 0; k0 < 1024; k0 += 32) {
    char* CUR = SM[(k0 >> 5) & 1];
    __syncthreads();  // drains prev stage (vmcnt0) + all waves done reading other buf
    if (k0 + 32 < 1024) stage(SM[((k0 >> 5) & 1) ^ 1], k0 + 32);

    short8 ah[4], al[4], bh[4], bl[4];
    if constexpr (AFP32) {
      const float* SA = (const float*)CUR;
#pragma unroll
      for (int f = 0; f < 4; ++f) {
        const int ra = wm * 64 + f * 16 + r16;
        const int ad = ra * 32 + SW4(kg, ra) * 8;
        f32x4 x0 = *(const f32x4*)&SA[ad];
        f32x4 x1 = *(const f32x4*)&SA[ad + 4];
        U8 H, L;
        splitpk(x0[0], x0[1], H.u[0], L.u[0]);
        splitpk(x0[2], x0[3], H.u[1], L.u[1]);
        splitpk(x1[0], x1[1], H.u[2], L.u[2]);
        splitpk(x1[2], x1[3], H.u[3], L.u[3]);
        ah[f] = H.s8; al[f] = L.s8;
      }
      const ushort* SBh = (const ushort*)(CUR + 16384);
      const ushort* SBl = (const ushort*)(CUR + 24576);
#pragma unroll
      for (int f = 0; f < 4; ++f) {
        const int rb = wn * 64 + f * 16 + r16;
        const int ab = rb * 32 + SW4(kg, rb) * 8;
        bh[f] = *(const short8*)&SBh[ab];
        bl[f] = *(const short8*)&SBl[ab];
      }
    } else {
      const ushort* SAh = (const ushort*)CUR;
      const ushort* SAl = (const ushort*)(CUR + 8192);
      const ushort* SBh = (const ushort*)(CUR + 16384);
      const ushort* SBl = (const ushort*)(CUR + 24576);
#pragma unroll
      for (int f = 0; f < 4; ++f) {
        const int ra = wm * 64 + f * 16 + r16;
        const int aa = ra * 32 + SW4(kg, ra) * 8;
        ah[f] = *(const short8*)&SAh[aa];
        al[f] = *(const short8*)&SAl[aa];
        const int rb = wn * 64 + f * 16 + r16;
        const int ab = rb * 32 + SW4(kg, rb) * 8;
        bh[f] = *(const short8*)&SBh[ab];
        bl[f] = *(const short8*)&SBl[ab];
      }
    }
    __builtin_amdgcn_s_setprio(1);
#pragma unroll
    for (int i = 0; i < 4; ++i)
#pragma unroll
      for (int j = 0; j < 4; ++j) {
        acc[i][j] = MFMA16(ah[i], bh[j], acc[i][j]);
        acc[i][j] = MFMA16(ah[i], bl[j], acc[i][j]);
        acc[i][j] = MFMA16(al[i], bh[j], acc[i][j]);
      }
    __builtin_amdgcn_s_setprio(0);
  }
}

// ---------------- QKV projection -------------------------------------------
template <bool PRESPLIT>
__global__ __launch_bounds__(256) void qkv_gemm(
    const float* __restrict__ x,
    const ushort* __restrict__ xh, const ushort* __restrict__ xl,
    const ushort* __restrict__ wqh, const ushort* __restrict__ wql,
    const ushort* __restrict__ wkh, const ushort* __restrict__ wkl,
    const ushort* __restrict__ wvh, const ushort* __restrict__ wvl,
    const float* __restrict__ bq, const float* __restrict__ bk,
    const float* __restrict__ bv,
    ushort* __restrict__ Qh, ushort* __restrict__ Ql,
    ushort* __restrict__ Kh, ushort* __restrict__ Kl,
    ushort* __restrict__ Vth, ushort* __restrict__ Vtl)
{
  const int ts = blockIdx.x >> 3;            // 0=Q 1=K 2=V
  const int n0 = (blockIdx.x & 7) * 128;
  const int m0 = blockIdx.y * 128;
  const ushort* Bh = (ts == 0) ? wqh : (ts == 1) ? wkh : wvh;
  const ushort* Bl = (ts == 0) ? wql : (ts == 1) ? wkl : wvl;
  const float* bias = (ts == 0) ? bq : (ts == 1) ? bk : bv;

  f32x4 zv = {0.f, 0.f, 0.f, 0.f};
  f32x4 acc[4][4];
#pragma unroll
  for (int i = 0; i < 4; ++i)
#pragma unroll
    for (int j = 0; j < 4; ++j) acc[i][j] = zv;

  if constexpr (PRESPLIT)
    gemm_core<false>(xh, xl, Bh, Bl, m0, n0, acc);
  else
    gemm_core<true>(x, nullptr, Bh, Bl, m0, n0, acc);

  const int lane = threadIdx.x & 63, w = threadIdx.x >> 6;
  const int wm = w >> 1, wn = w & 1, r16 = lane & 15, g4 = (lane >> 4) * 4;
  // Q pre-scale folds 1/sqrt(64) AND log2(e): softmax runs in exp2 domain.
  const float scale = (ts == 0) ? 0.18033688011112042f : 1.0f;
  ushort* H = (ts == 0) ? Qh : Kh;
  ushort* L = (ts == 0) ? Ql : Kl;
#pragma unroll
  for (int j = 0; j < 4; ++j) {
    const int nc = n0 + wn * 64 + j * 16 + r16;
    const float bb = bias[nc];
#pragma unroll
    for (int i = 0; i < 4; ++i) {
      const int mr = m0 + wm * 64 + i * 16 + g4;
      float v0 = (acc[i][j][0] + bb) * scale;
      float v1 = (acc[i][j][1] + bb) * scale;
      float v2 = (acc[i][j][2] + bb) * scale;
      float v3 = (acc[i][j][3] + bb) * scale;
      unsigned uh01, ul01, uh23, ul23;
      splitpk(v0, v1, uh01, ul01);
      splitpk(v2, v3, uh23, ul23);
      if (ts < 2) {      // Q/K: [b,t, h*64+d]
        size_t a0 = (size_t)mr * 1024 + nc;
        H[a0]        = (ushort)(uh01 & 0xffffu);
        H[a0 + 1024] = (ushort)(uh01 >> 16);
        H[a0 + 2048] = (ushort)(uh23 & 0xffffu);
        H[a0 + 3072] = (ushort)(uh23 >> 16);
        L[a0]        = (ushort)(ul01 & 0xffffu);
        L[a0 + 1024] = (ushort)(ul01 >> 16);
        L[a0 + 2048] = (ushort)(ul23 & 0xffffu);
        L[a0 + 3072] = (ushort)(ul23 >> 16);
      } else {           // V transposed scatter [b,h,d,t]
        const int b = mr >> 11, t0 = mr & 2047;
        const int hh = nc >> 6, d = nc & 63;
        size_t a0 = ((size_t)((b * 16 + hh) * 64 + d)) * 2048 + t0;
        *(unsigned*)&Vth[a0]     = uh01;
        *(unsigned*)&Vth[a0 + 2] = uh23;
        *(unsigned*)&Vtl[a0]     = ul01;
        *(unsigned*)&Vtl[a0 + 2] = ul23;
      }
    }
  }
}

// ---------------- flash attention (causal), split-bf16 MFMA --------------------
// 512 thr = 8 waves x 16 q-rows (QBLK=128); KV tile 64; double-buffered K/V.
// LDS = 64KB. P-hi reuses the dead K[cur] tile (8 x 2KB wave slices) after a
// mid-tile lgkm-only raw barrier (keeps prefetch vmcnt in flight).
// Plain launch bounds: round 9's (512,4) forced VGPR=64 + scratch spills.
__global__ __launch_bounds__(512) void attn(
    const ushort* __restrict__ Qh, const ushort* __restrict__ Ql,
    const ushort* __restrict__ Kgh, const ushort* __restrict__ Kgl,
    const ushort* __restrict__ Vth, const ushort* __restrict__ Vtl,
    ushort* __restrict__ AOh, ushort* __restrict__ AOl)
{
  // [buf][component: 0=Kh 1=Kl 2=Vh 3=Vl][64*64]
  __shared__ __align__(16) ushort KV[2][4][64 * 64];

  const int id = blockIdx.x;
  const int bh = id & 31;
  const int qr = id >> 5;                    // 0..15
  const int qt = (qr < 8) ? qr : 23 - qr;    // blocks (id, id+256) complementary
  const int b = bh >> 4, h = bh & 15;
  const int q0 = qt * 128;

  const int tid = threadIdx.x, lane = tid & 63, w = tid >> 6;  // w in 0..7
  const int r16 = lane & 15, lg = lane >> 4;
  const int lr8 = lane >> 3, ls8 = lane & 7;

  // 8-wave staging: wave w stages half (w&1) of component (w>>1).
  auto stageKV = [&](ushort (&BUF)[4][64 * 64], int k0) {
    const int comp = w >> 1;     // 0=Kh 1=Kl 2=Vh 3=Vl
    const int half = w & 1;      // rows 0-31 / 32-63
    char* dst = (char*)BUF[comp] + half * 4096;
    if (comp < 2) {              // K: LDS [t][64d], source d-slot swizzled
      const ushort* src = (comp == 0) ? Kgh : Kgl;
#pragma unroll
      for (int cc = 0; cc < 4; ++cc) {
        const int t = half * 32 + cc * 8 + lr8;
        const ushort* g = src + (size_t)(b * 2048 + k0 + t) * 1024 + h * 64 + SW8(ls8, t) * 8;
        gl_lds16(g, dst + cc * 1024);
      }
    } else {                     // V: LDS [d][64t], source t-slot swizzled
      const ushort* src = (comp == 2) ? Vth : Vtl;
#pragma unroll
      for (int cc = 0; cc < 4; ++cc) {
        const int d = half * 32 + cc * 8 + lr8;
        const ushort* g = src + (size_t)(bh * 64 + d) * 2048 + k0 + SW8(ls8, d) * 8;
        gl_lds16(g, dst + cc * 1024);
      }
    }
  };

  // Q fragments (pre-scaled, pre-split). A-frag: row=lane&15, k=(lane>>4)*8+j (+32s)
  short8 qfh[2], qfl[2];
#pragma unroll
  for (int s = 0; s < 2; ++s) {
    const int q = q0 + w * 16 + r16;
    size_t a = (size_t)(b * 2048 + q) * 1024 + h * 64 + 32 * s + lg * 8;
    qfh[s] = *(const short8*)&Qh[a];
    qfl[s] = *(const short8*)&Ql[a];
  }

  f32x4 zv = {0.f, 0.f, 0.f, 0.f};
  f32x4 o[4];
  float m_run[4], l_run[4];
#pragma unroll
  for (int nf = 0; nf < 4; ++nf) o[nf] = zv;
#pragma unroll
  for (int r = 0; r < 4; ++r) { m_run[r] = -INFINITY; l_run[r] = 0.f; }

  stageKV(KV[0], 0);  // prologue

  for (int k0 = 0; k0 < q0 + 128; k0 += 64) {
    const int pb = (k0 >> 6) & 1;
    __syncthreads();  // drains prev stage; all waves done reading other buf
    if (k0 + 64 < q0 + 128) stageKV(KV[pb ^ 1], k0 + 64);
    const ushort* KhL = KV[pb][0];
    const ushort* KlL = KV[pb][1];
    const ushort* VhL = KV[pb][2];
    const ushort* VlL = KV[pb][3];
    // wave-private 2KB P slice inside the (soon dead) K[cur] tile
    ushort* php = &KV[pb][w >> 2][(w & 3) * 1024];

    // S = Q K^T (3-term split)
    f32x4 sf[4];
#pragma unroll
    for (int nf = 0; nf < 4; ++nf) sf[nf] = zv;
#pragma unroll
    for (int s = 0; s < 2; ++s) {
      short8 kh_[4], kl_[4];
#pragma unroll
      for (int nf = 0; nf < 4; ++nf) {
        const int kv = nf * 16 + r16;
        const int ad = kv * 64 + SW8(4 * s + lg, kv) * 8;
        kh_[nf] = *(const short8*)&KhL[ad];
        kl_[nf] = *(const short8*)&KlL[ad];
      }
      __builtin_amdgcn_s_setprio(1);
#pragma unroll
      for (int nf = 0; nf < 4; ++nf) {
        sf[nf] = MFMA16(qfh[s], kh_[nf], sf[nf]);
        sf[nf] = MFMA16(qfh[s], kl_[nf], sf[nf]);
        sf[nf] = MFMA16(qfl[s], kh_[nf], sf[nf]);
      }
      __builtin_amdgcn_s_setprio(0);
    }

    // Mid-tile barrier: all waves' K ds_reads complete (lgkm only — the
    // in-flight global_load_lds prefetch is vmcnt and stays in flight).
    asm volatile("s_waitcnt lgkmcnt(0)\n\ts_barrier" ::: "memory");

    // causal mask + online softmax (exp2 domain); C/D: row=(lane>>4)*4+r, col=lane&15
#pragma unroll
    for (int r = 0; r < 4; ++r) {
      const int qg = q0 + w * 16 + lg * 4 + r;
#pragma unroll
      for (int nf = 0; nf < 4; ++nf) {
        const int kvg = k0 + nf * 16 + r16;
        if (kvg > qg) sf[nf][r] = -INFINITY;
      }
      float mx = fmaxf(fmaxf(sf[0][r], sf[1][r]), fmaxf(sf[2][r], sf[3][r]));
      mx = fmaxf(mx, __shfl_xor(mx, 1));
      mx = fmaxf(mx, __shfl_xor(mx, 2));
      mx = fmaxf(mx, __shfl_xor(mx, 4));
      mx = fmaxf(mx, __shfl_xor(mx, 8));
      const float mn = fmaxf(m_run[r], mx);
      const float al_ = __builtin_amdgcn_exp2f(m_run[r] - mn);
      float ps = 0.f;
#pragma unroll
      for (int nf = 0; nf < 4; ++nf) {
        const float p = __builtin_amdgcn_exp2f(sf[nf][r] - mn);
        sf[nf][r] = p;
        ps += p;
      }
      ps += __shfl_xor(ps, 1); ps += __shfl_xor(ps, 2);
      ps += __shfl_xor(ps, 4); ps += __shfl_xor(ps, 8);
      l_run[r] = l_run[r] * al_ + ps;
      m_run[r] = mn;
#pragma unroll
      for (int nf = 0; nf < 4; ++nf) o[nf][r] *= al_;
      // stage P hi (wave-private slice, swizzled; same-wave RAW, no barrier)
      const unsigned uh01 = pk2(sf[0][r], sf[1][r]);
      const unsigned uh23 = pk2(sf[2][r], sf[3][r]);
      const int row = lg * 4 + r;
      const int p7 = r16 & 7, hi8 = r16 >> 3;
      php[row * 64 + SW8(0 + hi8, row) * 8 + p7] = (ushort)(uh01 & 0xffffu);
      php[row * 64 + SW8(2 + hi8, row) * 8 + p7] = (ushort)(uh01 >> 16);
      php[row * 64 + SW8(4 + hi8, row) * 8 + p7] = (ushort)(uh23 & 0xffffu);
      php[row * 64 + SW8(6 + hi8, row) * 8 + p7] = (ushort)(uh23 >> 16);
    }

    // O += P V (P hi only; V hi+lo)
#pragma unroll
    for (int s2 = 0; s2 < 2; ++s2) {
      const int pad = r16 * 64 + SW8(4 * s2 + lg, r16) * 8;
      const short8 ph_ = *(const short8*)&php[pad];
      short8 vh_[4], vl_[4];
#pragma unroll
      for (int nf = 0; nf < 4; ++nf) {
        const int d = nf * 16 + r16;
        const int ad = d * 64 + SW8(4 * s2 + lg, d) * 8;
        vh_[nf] = *(const short8*)&VhL[ad];
        vl_[nf] = *(const short8*)&VlL[ad];
      }
      __builtin_amdgcn_s_setprio(1);
#pragma unroll
      for (int nf = 0; nf < 4; ++nf) {
        o[nf] = MFMA16(ph_, vh_[nf], o[nf]);
        o[nf] = MFMA16(ph_, vl_[nf], o[nf]);
      }
      __builtin_amdgcn_s_setprio(0);
    }
  }

  // epilogue: normalize, split, write AO hi/lo (aliases Qh/Ql — disjoint ownership)
#pragma unroll
  for (int r = 0; r < 4; ++r) {
    const float inv = 1.f / l_run[r];
    const int q = q0 + w * 16 + lg * 4 + r;
    const size_t base = (size_t)(b * 2048 + q) * 1024 + h * 64;
    unsigned uh01, ul01, uh23, ul23;
    splitpk(o[0][r] * inv, o[1][r] * inv, uh01, ul01);
    splitpk(o[2][r] * inv, o[3][r] * inv, uh23, ul23);
    AOh[base + r16]      = (ushort)(uh01 & 0xffffu);
    AOh[base + 16 + r16] = (ushort)(uh01 >> 16);
    AOh[base + 32 + r16] = (ushort)(uh23 & 0xffffu);
    AOh[base + 48 + r16] = (ushort)(uh23 >> 16);
    AOl[base + r16]      = (ushort)(ul01 & 0xffffu);
    AOl[base + 16 + r16] = (ushort)(ul01 >> 16);
    AOl[base + 32 + r16] = (ushort)(ul23 & 0xffffu);
    AOl[base + 48 + r16] = (ushort)(ul23 >> 16);
  }
}

// ---------------- output projection: AO @ Wo + bo -> out (fp32) ----------------
__global__ __launch_bounds__(256) void proj_gemm(
    const ushort* __restrict__ aoh, const ushort* __restrict__ aol,
    const ushort* __restrict__ woh, const ushort* __restrict__ wol,
    const float* __restrict__ bo, float* __restrict__ out)
{
  const int n0 = blockIdx.x * 128, m0 = blockIdx.y * 128;
  f32x4 zv = {0.f, 0.f, 0.f, 0.f};
  f32x4 acc[4][4];
#pragma unroll
  for (int i = 0; i < 4; ++i)
#pragma unroll
    for (int j = 0; j < 4; ++j) acc[i][j] = zv;

  gemm_core<false>(aoh, aol, woh, wol, m0, n0, acc);

  const int lane = threadIdx.x & 63, w = threadIdx.x >> 6;
  const int wm = w >> 1, wn = w & 1, r16 = lane & 15, g4 = (lane >> 4) * 4;
#pragma unroll
  for (int j = 0; j < 4; ++j) {
    const int nc = n0 + wn * 64 + j * 16 + r16;
    const float bb = bo[nc];
#pragma unroll
    for (int i = 0; i < 4; ++i) {
      const int mr = m0 + wm * 64 + i * 16 + g4;
#pragma unroll
      for (int r = 0; r < 4; ++r)
        out[(size_t)(mr + r) * 1024 + nc] = acc[i][j][r] + bb;
    }
  }
}

extern "C" void kernel_launch(void* const* d_in, const int* in_sizes, int n_in,
                              void* d_out, int out_size, void* d_ws, size_t ws_size,
                              hipStream_t stream) {
  const float* x  = (const float*)d_in[0];
  const float* Wq = (const float*)d_in[1];
  const float* bq = (const float*)d_in[2];
  const float* Wk = (const float*)d_in[3];
  const float* bk = (const float*)d_in[4];
  const float* Wv = (const float*)d_in[5];
  const float* bv = (const float*)d_in[6];
  const float* Wo = (const float*)d_in[7];
  const float* bo = (const float*)d_in[8];
  float* out = (float*)d_out;
  (void)in_sizes; (void)n_in; (void)out_size;

  const size_t MB = 1u << 20;
  char* ws = (char*)d_ws;
  ushort* Qh  = (ushort*)(ws + 0 * MB);
  ushort* Ql  = (ushort*)(ws + 8 * MB);
  ushort* Kh  = (ushort*)(ws + 16 * MB);
  ushort* Kl  = (ushort*)(ws + 24 * MB);
  ushort* Vth = (ushort*)(ws + 32 * MB);
  ushort* Vtl = (ushort*)(ws + 40 * MB);
  ushort* wqh = (ushort*)(ws + 48 * MB);
  ushort* wql = (ushort*)(ws + 50 * MB);
  ushort* wkh = (ushort*)(ws + 52 * MB);
  ushort* wkl = (ushort*)(ws + 54 * MB);
  ushort* wvh = (ushort*)(ws + 56 * MB);
  ushort* wvl = (ushort*)(ws + 58 * MB);
  ushort* woh = (ushort*)(ws + 60 * MB);
  ushort* wol = (ushort*)(ws + 62 * MB);
  ushort* AOh = Qh;   // alias: attn writes exactly the Q region it owns
  ushort* AOl = Ql;

  wprep<<<dim3(16, 16, 4), 256, 0, stream>>>(Wq, Wk, Wv, Wo,
                                             wqh, wql, wkh, wkl, wvh, wvl, woh, wol);
  if (ws_size >= 80 * MB) {
    ushort* xh = (ushort*)(ws + 64 * MB);
    ushort* xl = (ushort*)(ws + 72 * MB);
    xsplit<<<dim3(4096), 256, 0, stream>>>(x, xh, xl);
    qkv_gemm<true><<<dim3(24, 32), 256, 0, stream>>>(
        x, xh, xl, wqh, wql, wkh, wkl, wvh, wvl, bq, bk, bv,
        Qh, Ql, Kh, Kl, Vth, Vtl);
  } else {
    qkv_gemm<false><<<dim3(24, 32), 256, 0, stream>>>(
        x, nullptr, nullptr, wqh, wql, wkh, wkl, wvh, wvl, bq, bk, bv,
        Qh, Ql, Kh, Kl, Vth, Vtl);
  }
  attn<<<dim3(512), 512, 0, stream>>>(Qh, Ql, Kh, Kl, Vth, Vtl, AOh, AOl);
  proj_gemm<<<dim3(8, 32), 256, 0, stream>>>(AOh, AOl, woh, wol, bo, out);
}